// Round 1
// baseline (116.024 us; speedup 1.0000x reference)
//
#include <hip/hip_runtime.h>

typedef __attribute__((ext_vector_type(4))) float f32x4;
typedef __attribute__((ext_vector_type(8))) short bf16x8;

constexpr int Bsz = 4096, Asz = 32, Isz = 256, Osz = 256;
constexpr int BM = 64, BK = 32;
constexpr int LDK = 40;                 // padded bf16 row stride: 80B, 16B-aligned reads, ~2-way banks
constexpr int NKT = Isz / BK;           // 8 K-steps
constexpr int NBLK = Asz * (Bsz / BM);  // 32 * 64 = 2048 blocks

__device__ inline short f2bf(float f) {
    union { float f; unsigned u; } c; c.f = f;
    unsigned r = c.u + 0x7FFFu + ((c.u >> 16) & 1u);   // RNE
    return (short)(r >> 16);
}

__global__ __launch_bounds__(256) void al_gemm(const float* __restrict__ x,
                                               const float* __restrict__ w,
                                               const float* __restrict__ bias,
                                               float* __restrict__ out)
{
    __shared__ unsigned short sA[2][BM][LDK];    // 10.0 KB
    __shared__ unsigned short sB[2][Osz][LDK];   // 40.0 KB

    // XCD-contiguous bijective swizzle: each XCD gets 256 consecutive logical ids
    // = 4 full a-groups, so each w[a] lives in exactly one XCD's L2.
    const int p   = blockIdx.x;
    const int l   = (p & 7) * (NBLK / 8) + (p >> 3);
    const int a   = l >> 6;              // assignment
    const int b0  = (l & 63) * BM;       // batch-row base

    const int t    = threadIdx.x;
    const int wid  = t >> 6;
    const int lane = t & 63;
    const int llo  = lane & 15, lhi = lane >> 4;
    const int nb   = wid * 64;           // wave's N base (4 waves split N=256)

    // staging assignment: A tile 64x32 f32 -> thread (row=t>>2, 8 floats at (t&3)*8)
    //                     B tile 256x32 f32 -> thread = one O-row (32 floats)
    const int ar = t >> 2, aq = t & 3;
    const float* xA = x + ((size_t)b0 * Asz + a) * Isz;
    const float* wB = w + (size_t)a * Osz * Isz + (size_t)t * Isz;

    f32x4 acc[4][4];
#pragma unroll
    for (int m = 0; m < 4; ++m)
#pragma unroll
        for (int n = 0; n < 4; ++n) acc[m][n] = (f32x4)0.f;

    f32x4 va0, va1, vb[8];

    auto STAGE_LOAD = [&](int kt) {
        const float* pa = xA + (size_t)ar * (Asz * Isz) + kt * BK + aq * 8;
        va0 = *(const f32x4*)pa;
        va1 = *(const f32x4*)(pa + 4);
        const float* pb = wB + kt * BK;
#pragma unroll
        for (int q = 0; q < 8; ++q) vb[q] = *(const f32x4*)(pb + q * 4);
    };

    auto STAGE_WRITE = [&](int buf) {
        bf16x8 pk;
        pk[0] = f2bf(va0[0]); pk[1] = f2bf(va0[1]); pk[2] = f2bf(va0[2]); pk[3] = f2bf(va0[3]);
        pk[4] = f2bf(va1[0]); pk[5] = f2bf(va1[1]); pk[6] = f2bf(va1[2]); pk[7] = f2bf(va1[3]);
        *(bf16x8*)&sA[buf][ar][aq * 8] = pk;
#pragma unroll
        for (int q = 0; q < 4; ++q) {
            bf16x8 pb2;
            pb2[0] = f2bf(vb[2*q][0]);   pb2[1] = f2bf(vb[2*q][1]);
            pb2[2] = f2bf(vb[2*q][2]);   pb2[3] = f2bf(vb[2*q][3]);
            pb2[4] = f2bf(vb[2*q+1][0]); pb2[5] = f2bf(vb[2*q+1][1]);
            pb2[6] = f2bf(vb[2*q+1][2]); pb2[7] = f2bf(vb[2*q+1][3]);
            *(bf16x8*)&sB[buf][t][q * 8] = pb2;
        }
    };

    auto COMPUTE = [&](int buf) {
        bf16x8 aF[4], bF[4];
#pragma unroll
        for (int m = 0; m < 4; ++m)
            aF[m] = *(const bf16x8*)&sA[buf][m * 16 + llo][lhi * 8];
#pragma unroll
        for (int n = 0; n < 4; ++n)
            bF[n] = *(const bf16x8*)&sB[buf][nb + n * 16 + llo][lhi * 8];
#pragma unroll
        for (int m = 0; m < 4; ++m)
#pragma unroll
            for (int n = 0; n < 4; ++n)
                acc[m][n] = __builtin_amdgcn_mfma_f32_16x16x32_bf16(aF[m], bF[n], acc[m][n], 0, 0, 0);
    };

    STAGE_LOAD(0);
    STAGE_WRITE(0);
    __syncthreads();

    int cur = 0;
#pragma unroll
    for (int kt = 0; kt < NKT - 1; ++kt) {
        STAGE_LOAD(kt + 1);      // issue next-tile global loads (latency hides under MFMA)
        COMPUTE(cur);            // MFMA on current buffer
        STAGE_WRITE(cur ^ 1);    // cvt + ds_write into the other buffer
        __syncthreads();
        cur ^= 1;
    }
    COMPUTE(cur);

    // epilogue: D[m=(lane>>4)*4+r][n=lane&15] per 16x16 fragment (m89-verified layout)
#pragma unroll
    for (int n = 0; n < 4; ++n) {
        const int col = nb + n * 16 + llo;
        const float bv = bias[a * Osz + col];
#pragma unroll
        for (int m = 0; m < 4; ++m) {
            const int row = b0 + m * 16 + lhi * 4;
            float* op = out + ((size_t)row * Asz + a) * Osz + col;
#pragma unroll
            for (int r = 0; r < 4; ++r)
                op[(size_t)r * Asz * Osz] = acc[m][n][r] + bv;
        }
    }
}

extern "C" void kernel_launch(void* const* d_in, const int* in_sizes, int n_in,
                              void* d_out, int out_size, void* d_ws, size_t ws_size,
                              hipStream_t stream) {
    const float* x    = (const float*)d_in[0];
    const float* w    = (const float*)d_in[1];
    const float* bias = (const float*)d_in[2];
    float* out        = (float*)d_out;
    al_gemm<<<dim3(NBLK), dim3(256), 0, stream>>>(x, w, bias, out);
}